// Round 4
// baseline (703.990 us; speedup 1.0000x reference)
//
#include <hip/hip_runtime.h>
#include <hip/hip_bf16.h>

typedef unsigned int u32;
typedef unsigned short u16;

// bf16 = top 16 bits of fp32; RNE pack
static __device__ __forceinline__ float bflo(u32 u) { return __uint_as_float(u << 16); }
static __device__ __forceinline__ float bfhi(u32 u) { return __uint_as_float(u & 0xFFFF0000u); }
static __device__ __forceinline__ float bf2f(u16 u) { return __uint_as_float((u32)u << 16); }
static __device__ __forceinline__ u32 f2bf(float f) {
    u32 u = __float_as_uint(f);
    return (u + 0x7FFFu + ((u >> 16) & 1u)) >> 16;  // round-to-nearest-even
}
static __device__ __forceinline__ u32 packbf(float lo, float hi) {
    return f2bf(lo) | (f2bf(hi) << 16);
}
// dtype-flexible input load: flag==0 -> bf16 array, flag==1 -> f32 array (same element index)
static __device__ __forceinline__ float ldf(const u16* p16, int idx, int isf32) {
    return isf32 ? ((const float*)p16)[idx] : bf2f(p16[idx]);
}
static __device__ __forceinline__ float sanitize(float v, float code) {
    return (fabsf(v) < 1e30f) ? v : code;  // NaN/Inf -> finite sentinel (diagnostic)
}

static __device__ __forceinline__ float wave_sum(float v) {
#pragma unroll
    for (int o = 32; o; o >>= 1) v += __shfl_xor(v, o, 64);
    return v;
}

// ---------------- diagnostics ----------------

__global__ void k_sentinel(float* __restrict__ out, int n, float val) {
    int i = blockIdx.x * blockDim.x + threadIdx.x;
    if (i < n) out[i] = val;
}

// decide input dtype: inspect first 4096 u16s of x; bf16 N(0,1) has exponent in [96,135],
// f32-as-u16 has ~40%+ of u16s (mantissa halves) with wild exponent fields.
__global__ void k_sniff(const u16* __restrict__ x, int* __restrict__ flag) {
    int lane = threadIdx.x;  // 64 threads
    int wild = 0;
    for (int i = 0; i < 64; i++) {
        u32 u = x[lane * 64 + i];
        int e = (u >> 7) & 0xFF;
        if (e < 96 || e > 135) wild++;
    }
    float tot = wave_sum((float)wild);
    if (lane == 0) *flag = (tot > 200.f) ? 1 : 0;
}

__global__ void k_zero(int* __restrict__ p, int n) {
    int i = blockIdx.x * blockDim.x + threadIdx.x;
    if (i < n) p[i] = 0;
}

// ---------------- sort-by-dst machinery ----------------

__global__ void k_hist(const int* __restrict__ dst, int E, int* __restrict__ deg) {
    int i = blockIdx.x * blockDim.x + threadIdx.x;
    if (i < E) atomicAdd(&deg[dst[i]], 1);
}

__global__ void k_scan_partial(const int* __restrict__ deg, int n, int* __restrict__ bsum) {
    int t = threadIdx.x;
    int base = blockIdx.x * 1024 + t * 4;
    int s = 0;
#pragma unroll
    for (int j = 0; j < 4; j++) {
        int idx = base + j;
        if (idx < n) s += deg[idx];
    }
    __shared__ int sh[256];
    sh[t] = s;
    __syncthreads();
    for (int d = 128; d; d >>= 1) {
        if (t < d) sh[t] += sh[t + d];
        __syncthreads();
    }
    if (t == 0) bsum[blockIdx.x] = sh[0];
}

__global__ void k_scan_bsum(const int* __restrict__ bsum, int nb, int* __restrict__ boff) {
    int t = threadIdx.x;  // 256 threads
    int v = (t < nb) ? bsum[t] : 0;
    __shared__ int sh[256];
    sh[t] = v;
    __syncthreads();
    for (int d = 1; d < 256; d <<= 1) {
        int u = (t >= d) ? sh[t - d] : 0;
        __syncthreads();
        sh[t] += u;
        __syncthreads();
    }
    if (t < nb) boff[t] = sh[t] - v;  // exclusive
}

__global__ void k_scan_final(const int* __restrict__ deg, int n, const int* __restrict__ boff,
                             int* __restrict__ offsets, int Etot) {
    int t = threadIdx.x;
    int base = blockIdx.x * 1024 + t * 4;
    int v[4];
    int s = 0;
#pragma unroll
    for (int j = 0; j < 4; j++) {
        int idx = base + j;
        v[j] = (idx < n) ? deg[idx] : 0;
        s += v[j];
    }
    __shared__ int sh[256];
    sh[t] = s;
    __syncthreads();
    for (int d = 1; d < 256; d <<= 1) {
        int u = (t >= d) ? sh[t - d] : 0;
        __syncthreads();
        sh[t] += u;
        __syncthreads();
    }
    int ex = sh[t] - s + boff[blockIdx.x];
#pragma unroll
    for (int j = 0; j < 4; j++) {
        int idx = base + j;
        if (idx < n) offsets[idx] = ex;
        ex += v[j];
    }
    if (blockIdx.x == 0 && t == 0) offsets[n] = Etot;
}

__global__ void k_scatter(const int* __restrict__ src, const int* __restrict__ dst,
                          const u16* __restrict__ avl, const u16* __restrict__ avh,
                          const int* __restrict__ lab, int E,
                          const int* __restrict__ offsets, int* __restrict__ cursor,
                          int* __restrict__ ssrcf, u32* __restrict__ svlh,
                          const int* __restrict__ flag) {
    int i = blockIdx.x * blockDim.x + threadIdx.x;
    if (i >= E) return;
    int isf32 = *flag;
    int d = dst[i];
    int pos = offsets[d] + atomicAdd(&cursor[d], 1);
    if ((unsigned)pos >= (unsigned)E) return;
    int s = src[i];
    int sl = lab[s], dl = lab[d];
    int fake = (sl < 0 || dl < 0) ? 2 : ((sl != dl) ? 1 : 0);
    ssrcf[pos] = s | (fake << 20);
    svlh[pos] = isf32 ? packbf(((const float*)avl)[i], ((const float*)avh)[i])
                      : ((u32)avl[i] | ((u32)avh[i] << 16));
}

// ---------------- phase A: x @ {W_low, W_high, W_mlp} ----------------
// xwlh: packed bf16 pair (workspace). omlp: f32, staged in d_out.

__launch_bounds__(256) __global__
void k_gemm(const u16* __restrict__ x, const u16* __restrict__ wl, const u16* __restrict__ wh,
            const u16* __restrict__ wm, int N, u32* __restrict__ xwlh, float* __restrict__ omlp,
            const int* __restrict__ flag) {
    int isf32 = *flag;
    __shared__ float WL[4096], WH[4096], WM[4096];
    for (int i = threadIdx.x; i < 4096; i += 256) {
        WL[i] = ldf(wl, i, isf32);
        WH[i] = ldf(wh, i, isf32);
        WM[i] = ldf(wm, i, isf32);
    }
    __syncthreads();
    int lane = threadIdx.x & 63;
    int wid = (blockIdx.x * 256 + threadIdx.x) >> 6;
    int nw = gridDim.x * 4;
    for (int r0 = wid * 8; r0 < N; r0 += nw * 8) {
        float xv[8];
#pragma unroll
        for (int j = 0; j < 8; j++) xv[j] = ldf(x, (r0 + j) * 64 + lane, isf32);
        float aL[8], aH[8], aM[8];
#pragma unroll
        for (int j = 0; j < 8; j++) { aL[j] = 0.f; aH[j] = 0.f; aM[j] = 0.f; }
        for (int k = 0; k < 64; k++) {
            float wlv = WL[k * 64 + lane];
            float whv = WH[k * 64 + lane];
            float wmv = WM[k * 64 + lane];
#pragma unroll
            for (int j = 0; j < 8; j++) {
                float xk = __shfl(xv[j], k, 64);
                aL[j] += xk * wlv;
                aH[j] += xk * whv;
                aM[j] += xk * wmv;
            }
        }
#pragma unroll
        for (int j = 0; j < 8; j++) {
            size_t o = (size_t)(r0 + j) * 64 + lane;
            xwlh[o] = packbf(sanitize(aL[j], 111.f), sanitize(aH[j], 111.f));
            omlp[o] = fmaxf(sanitize(aM[j], 111.f), 0.f);
        }
    }
}

// ---------------- phase B: spmm + relu, one wave per dst node ----------------

__launch_bounds__(256) __global__
void k_spmm(const u32* __restrict__ xwlh, const int* __restrict__ ssrcf,
            const u32* __restrict__ svlh, const int* __restrict__ offsets, int N,
            u32* __restrict__ outlh) {
    int wid = (blockIdx.x * blockDim.x + threadIdx.x) >> 6;
    int lane = threadIdx.x & 63;
    if (wid >= N) return;
    int s = offsets[wid], e = offsets[wid + 1];
    float al = 0.f, ah = 0.f;
    for (int base = s; base < e; base += 64) {
        int cnt = min(64, e - base);
        int sf = 0;
        u32 vv = 0;
        if (lane < cnt) {
            sf = ssrcf[base + lane];
            vv = svlh[base + lane];
        }
        for (int j = 0; j < cnt; j++) {
            int sj = __shfl(sf, j, 64) & 0xFFFFF;
            sj = min(sj, N - 1);
            u32 vj = (u32)__shfl((int)vv, j, 64);
            u32 xw = xwlh[(size_t)sj * 64 + lane];
            al += bflo(vj) * bflo(xw);
            ah += bfhi(vj) * bfhi(xw);
        }
    }
    outlh[(size_t)wid * 64 + lane] =
        packbf(fmaxf(sanitize(al, 222.f), 0.f), fmaxf(sanitize(ah, 222.f), 0.f));
}

// ---------------- phase C+D fused: masked aggregation + attention ----------------
// omlp is read from d_out (f32), final output written over it (f32).

__launch_bounds__(256) __global__
void k_agg(const u32* __restrict__ outlh, const int* __restrict__ ssrcf,
           const int* __restrict__ offsets,
           const u16* __restrict__ aLF, const u16* __restrict__ aHF,
           const u16* __restrict__ aLB, const u16* __restrict__ aHB,
           const u16* __restrict__ aLU, const u16* __restrict__ aHU,
           const u16* __restrict__ aM, const u16* __restrict__ a7, int N,
           float* __restrict__ out, const int* __restrict__ flag) {
    int isf32 = *flag;
    int wid = (blockIdx.x * blockDim.x + threadIdx.x) >> 6;
    int lane = threadIdx.x & 63;
    if (wid >= N) return;
    int s = offsets[wid], e = offsets[wid + 1];
    float hetL = 0.f, hetH = 0.f, homL = 0.f, homH = 0.f, unkL = 0.f, unkH = 0.f;
    for (int base = s; base < e; base += 64) {
        int cnt = min(64, e - base);
        int sf = 0;
        if (lane < cnt) sf = ssrcf[base + lane];
        for (int j = 0; j < cnt; j++) {
            int t = __shfl(sf, j, 64);
            int sj = min(t & 0xFFFFF, N - 1);
            int fj = (t >> 20) & 3;
            u32 o = outlh[(size_t)sj * 64 + lane];
            float lo = bflo(o), hi = bfhi(o);
            if (fj == 0) { homL += lo; homH += hi; }
            else if (fj == 1) { hetL += lo; hetH += hi; }
            else { unkL += lo; unkH += hi; }
        }
    }
    float mv = out[(size_t)wid * 64 + lane];  // omlp staged in d_out (f32)

    float d0 = wave_sum(hetL * ldf(aLF, lane, isf32));
    float d1 = wave_sum(hetH * ldf(aHF, lane, isf32));
    float d2 = wave_sum(homL * ldf(aLB, lane, isf32));
    float d3 = wave_sum(homH * ldf(aHB, lane, isf32));
    float d4 = wave_sum(unkL * ldf(aLU, lane, isf32));
    float d5 = wave_sum(unkH * ldf(aHU, lane, isf32));
    float d6 = wave_sum(mv * ldf(aM, lane, isf32));

    float f[7];
    f[0] = 1.f / (1.f + expf(-d0));
    f[1] = 1.f / (1.f + expf(-d1));
    f[2] = 1.f / (1.f + expf(-d2));
    f[3] = 1.f / (1.f + expf(-d3));
    f[4] = 1.f / (1.f + expf(-d4));
    f[5] = 1.f / (1.f + expf(-d5));
    f[6] = 1.f / (1.f + expf(-d6));

    float z[7];
#pragma unroll
    for (int j = 0; j < 7; j++) {
        float acc = 0.f;
#pragma unroll
        for (int i = 0; i < 7; i++) acc += f[i] * ldf(a7, i * 7 + j, isf32);
        z[j] = acc * (1.f / 7.f);
    }
    float m = z[0];
#pragma unroll
    for (int j = 1; j < 7; j++) m = fmaxf(m, z[j]);
    float wsum = 0.f;
    float wv[7];
#pragma unroll
    for (int j = 0; j < 7; j++) { wv[j] = expf(z[j] - m); wsum += wv[j]; }

    float o = wv[0] * hetL + wv[1] * hetH + wv[2] * homL + wv[3] * homH + wv[4] * unkL +
              wv[5] * unkH + wv[6] * mv;
    o *= 7.f / wsum;
    out[(size_t)wid * 64 + lane] = sanitize(o, 333.f);
}

// ---------------- launcher ----------------

extern "C" void kernel_launch(void* const* d_in, const int* in_sizes, int n_in, void* d_out,
                              int out_size, void* d_ws, size_t ws_size, hipStream_t stream) {
    const u16* x = (const u16*)d_in[0];
    const u16* avl = (const u16*)d_in[1];
    const u16* avh = (const u16*)d_in[2];
    const u16* wl = (const u16*)d_in[3];
    const u16* wh = (const u16*)d_in[4];
    const u16* wm = (const u16*)d_in[5];
    const u16* aLF = (const u16*)d_in[6];
    const u16* aHF = (const u16*)d_in[7];
    const u16* aLB = (const u16*)d_in[8];
    const u16* aHB = (const u16*)d_in[9];
    const u16* aLU = (const u16*)d_in[10];
    const u16* aHU = (const u16*)d_in[11];
    const u16* aM = (const u16*)d_in[12];
    const u16* a7 = (const u16*)d_in[13];
    const int* esrc = (const int*)d_in[14];
    const int* edst = (const int*)d_in[15];
    const int* lab = (const int*)d_in[16];
    float* out = (float*)d_out;  // reference output is jnp.float32

    const int N = in_sizes[0] / 64;
    const int E = in_sizes[1];

    char* w = (char*)d_ws;
    size_t off = 0;
    auto alloc = [&](size_t bytes) -> char* {
        char* p = w + off;
        off += (bytes + 255) & ~(size_t)255;
        return p;
    };
    // small/critical first
    int* flag = (int*)alloc(256);
    int* offsets = (int*)alloc((size_t)(N + 1) * 4);
    int* degcur = (int*)alloc((size_t)2 * N * 4);
    int* bsum = (int*)alloc(256 * 4);
    int* boff = (int*)alloc(256 * 4);
    int* ssrcf = (int*)alloc((size_t)E * 4);
    u32* svlh = (u32*)alloc((size_t)E * 4);
    u32* xwlh = (u32*)alloc((size_t)N * 64 * 4);
    u32* outlh = (u32*)alloc((size_t)N * 64 * 4);
    int* deg = degcur;
    int* cursor = degcur + N;

    // diagnostic: workspace too small -> sentinel 1000.0, do nothing else
    if (ws_size < off) {
        k_sentinel<<<(out_size + 255) / 256, 256, 0, stream>>>(out, out_size, 1000.0f);
        return;
    }

    int NB = (N + 1023) / 1024;  // 98 for N=100000; must be <= 256

    k_sniff<<<1, 64, 0, stream>>>(x, flag);
    k_zero<<<(2 * N + 255) / 256, 256, 0, stream>>>(degcur, 2 * N);
    k_hist<<<(E + 255) / 256, 256, 0, stream>>>(edst, E, deg);
    k_scan_partial<<<NB, 256, 0, stream>>>(deg, N, bsum);
    k_scan_bsum<<<1, 256, 0, stream>>>(bsum, NB, boff);
    k_scan_final<<<NB, 256, 0, stream>>>(deg, N, boff, offsets, E);
    k_scatter<<<(E + 255) / 256, 256, 0, stream>>>(esrc, edst, avl, avh, lab, E, offsets, cursor,
                                                   ssrcf, svlh, flag);

    k_gemm<<<512, 256, 0, stream>>>(x, wl, wh, wm, N, xwlh, out /* omlp staged in d_out */, flag);

    int nodeBlocks = (N * 64 + 255) / 256;
    k_spmm<<<nodeBlocks, 256, 0, stream>>>(xwlh, ssrcf, svlh, offsets, N, outlh);
    k_agg<<<nodeBlocks, 256, 0, stream>>>(outlh, ssrcf, offsets, aLF, aHF, aLB, aHB, aLU, aHU, aM,
                                          a7, N, out, flag);
}

// Round 5
// 624.877 us; speedup vs baseline: 1.1266x; 1.1266x over previous
//
#include <hip/hip_runtime.h>
#include <hip/hip_bf16.h>

typedef unsigned int u32;
typedef unsigned short u16;

// bf16 = top 16 bits of fp32; RNE pack
static __device__ __forceinline__ float bflo(u32 u) { return __uint_as_float(u << 16); }
static __device__ __forceinline__ float bfhi(u32 u) { return __uint_as_float(u & 0xFFFF0000u); }
static __device__ __forceinline__ float bf2f(u16 u) { return __uint_as_float((u32)u << 16); }
static __device__ __forceinline__ u32 f2bf(float f) {
    u32 u = __float_as_uint(f);
    return (u + 0x7FFFu + ((u >> 16) & 1u)) >> 16;  // round-to-nearest-even
}
static __device__ __forceinline__ u32 packbf(float lo, float hi) {
    return f2bf(lo) | (f2bf(hi) << 16);
}
// dtype-flexible input load: flag==0 -> bf16 array, flag==1 -> f32 array
static __device__ __forceinline__ float ldf(const u16* p16, int idx, int isf32) {
    return isf32 ? ((const float*)p16)[idx] : bf2f(p16[idx]);
}
static __device__ __forceinline__ float sanitize(float v, float code) {
    return (fabsf(v) < 1e30f) ? v : code;
}

static __device__ __forceinline__ float wave_sum(float v) {
#pragma unroll
    for (int o = 32; o; o >>= 1) v += __shfl_xor(v, o, 64);
    return v;
}

// ---------------- diagnostics / utility ----------------

__global__ void k_sentinel(float* __restrict__ out, int n, float val) {
    int i = blockIdx.x * blockDim.x + threadIdx.x;
    if (i < n) out[i] = val;
}

// zero p[0:n]; block 0's first wave also sniffs input dtype (bf16 vs f32-as-u16)
__global__ void k_zero_sniff(int* __restrict__ p, int n, const u16* __restrict__ x,
                             int* __restrict__ flag) {
    int i = blockIdx.x * blockDim.x + threadIdx.x;
    if (i < n) p[i] = 0;
    if (blockIdx.x == 0 && threadIdx.x < 64) {
        int lane = threadIdx.x;
        int wild = 0;
        for (int k = 0; k < 64; k++) {
            u32 u = x[lane * 64 + k];
            int e = (u >> 7) & 0xFF;
            if (e < 96 || e > 135) wild++;
        }
        float tot = wave_sum((float)wild);
        if (lane == 0) *flag = (tot > 200.f) ? 1 : 0;
    }
}

// ---------------- sort-by-dst machinery ----------------

__global__ void k_hist(const int* __restrict__ dst, int E, int* __restrict__ deg) {
    int i = blockIdx.x * blockDim.x + threadIdx.x;
    if (i < E) atomicAdd(&deg[dst[i]], 1);
}

__global__ void k_scan_partial(const int* __restrict__ deg, int n, int* __restrict__ bsum) {
    int t = threadIdx.x;
    int base = blockIdx.x * 1024 + t * 4;
    int s = 0;
#pragma unroll
    for (int j = 0; j < 4; j++) {
        int idx = base + j;
        if (idx < n) s += deg[idx];
    }
    __shared__ int sh[256];
    sh[t] = s;
    __syncthreads();
    for (int d = 128; d; d >>= 1) {
        if (t < d) sh[t] += sh[t + d];
        __syncthreads();
    }
    if (t == 0) bsum[blockIdx.x] = sh[0];
}

__global__ void k_scan_bsum(const int* __restrict__ bsum, int nb, int* __restrict__ boff) {
    int t = threadIdx.x;  // 256 threads
    int v = (t < nb) ? bsum[t] : 0;
    __shared__ int sh[256];
    sh[t] = v;
    __syncthreads();
    for (int d = 1; d < 256; d <<= 1) {
        int u = (t >= d) ? sh[t - d] : 0;
        __syncthreads();
        sh[t] += u;
        __syncthreads();
    }
    if (t < nb) boff[t] = sh[t] - v;  // exclusive
}

__global__ void k_scan_final(const int* __restrict__ deg, int n, const int* __restrict__ boff,
                             int* __restrict__ offsets, int Etot) {
    int t = threadIdx.x;
    int base = blockIdx.x * 1024 + t * 4;
    int v[4];
    int s = 0;
#pragma unroll
    for (int j = 0; j < 4; j++) {
        int idx = base + j;
        v[j] = (idx < n) ? deg[idx] : 0;
        s += v[j];
    }
    __shared__ int sh[256];
    sh[t] = s;
    __syncthreads();
    for (int d = 1; d < 256; d <<= 1) {
        int u = (t >= d) ? sh[t - d] : 0;
        __syncthreads();
        sh[t] += u;
        __syncthreads();
    }
    int ex = sh[t] - s + boff[blockIdx.x];
#pragma unroll
    for (int j = 0; j < 4; j++) {
        int idx = base + j;
        if (idx < n) offsets[idx] = ex;
        ex += v[j];
    }
    if (blockIdx.x == 0 && t == 0) offsets[n] = Etot;
}

__global__ void k_scatter(const int* __restrict__ src, const int* __restrict__ dst,
                          const u16* __restrict__ avl, const u16* __restrict__ avh,
                          const int* __restrict__ lab, int E,
                          const int* __restrict__ offsets, int* __restrict__ cursor,
                          int* __restrict__ ssrcf, u32* __restrict__ svlh,
                          const int* __restrict__ flag) {
    int i = blockIdx.x * blockDim.x + threadIdx.x;
    if (i >= E) return;
    int isf32 = *flag;
    int d = dst[i];
    int pos = offsets[d] + atomicAdd(&cursor[d], 1);
    if ((unsigned)pos >= (unsigned)E) return;
    int s = src[i];
    int sl = lab[s], dl = lab[d];
    int fake = (sl < 0 || dl < 0) ? 2 : ((sl != dl) ? 1 : 0);
    ssrcf[pos] = s | (fake << 20);
    svlh[pos] = isf32 ? packbf(((const float*)avl)[i], ((const float*)avh)[i])
                      : ((u32)avl[i] | ((u32)avh[i] << 16));
}

// ---------------- phase A: x @ {W_low, W_high, W_mlp} ----------------

__launch_bounds__(256) __global__
void k_gemm(const u16* __restrict__ x, const u16* __restrict__ wl, const u16* __restrict__ wh,
            const u16* __restrict__ wm, int N, u32* __restrict__ xwlh, float* __restrict__ omlp,
            const int* __restrict__ flag) {
    int isf32 = *flag;
    __shared__ float WL[4096], WH[4096], WM[4096];
    for (int i = threadIdx.x; i < 4096; i += 256) {
        WL[i] = ldf(wl, i, isf32);
        WH[i] = ldf(wh, i, isf32);
        WM[i] = ldf(wm, i, isf32);
    }
    __syncthreads();
    int lane = threadIdx.x & 63;
    int wid = (blockIdx.x * 256 + threadIdx.x) >> 6;
    int nw = gridDim.x * 4;
    for (int r0 = wid * 8; r0 < N; r0 += nw * 8) {
        float xv[8];
#pragma unroll
        for (int j = 0; j < 8; j++) xv[j] = ldf(x, (r0 + j) * 64 + lane, isf32);
        float aL[8], aH[8], aM[8];
#pragma unroll
        for (int j = 0; j < 8; j++) { aL[j] = 0.f; aH[j] = 0.f; aM[j] = 0.f; }
        for (int k = 0; k < 64; k++) {
            float wlv = WL[k * 64 + lane];
            float whv = WH[k * 64 + lane];
            float wmv = WM[k * 64 + lane];
#pragma unroll
            for (int j = 0; j < 8; j++) {
                float xk = __shfl(xv[j], k, 64);
                aL[j] += xk * wlv;
                aH[j] += xk * whv;
                aM[j] += xk * wmv;
            }
        }
#pragma unroll
        for (int j = 0; j < 8; j++) {
            size_t o = (size_t)(r0 + j) * 64 + lane;
            xwlh[o] = packbf(sanitize(aL[j], 111.f), sanitize(aH[j], 111.f));
            omlp[o] = fmaxf(sanitize(aM[j], 111.f), 0.f);
        }
    }
}

// ---------------- phase B: spmm + relu, one wave per dst node ----------------
// Edge payload read via wave-uniform (scalar) loads; row gathers prefetched 8-deep.

__launch_bounds__(256) __global__
void k_spmm(const u32* __restrict__ xwlh, const int* __restrict__ ssrcf,
            const u32* __restrict__ svlh, const int* __restrict__ offsets, int N,
            u32* __restrict__ outlh) {
    int wid = __builtin_amdgcn_readfirstlane((blockIdx.x * blockDim.x + threadIdx.x) >> 6);
    int lane = threadIdx.x & 63;
    if (wid >= N) return;
    int s = offsets[wid], e = offsets[wid + 1];
    int Nm1 = N - 1;
    float al = 0.f, ah = 0.f;
    int j = s;
    for (; j + 8 <= e; j += 8) {
        u32 row[8], val[8];
#pragma unroll
        for (int t = 0; t < 8; t++) {
            int sf = ssrcf[j + t];        // scalar load (wave-uniform)
            val[t] = svlh[j + t];         // scalar load
            int sj = min(sf & 0xFFFFF, Nm1);
            row[t] = xwlh[(size_t)sj * 64 + lane];  // vector gather, 8 in flight
        }
#pragma unroll
        for (int t = 0; t < 8; t++) {
            al += bflo(val[t]) * bflo(row[t]);
            ah += bfhi(val[t]) * bfhi(row[t]);
        }
    }
    for (; j < e; j++) {
        int sf = ssrcf[j];
        u32 vv = svlh[j];
        int sj = min(sf & 0xFFFFF, Nm1);
        u32 xw = xwlh[(size_t)sj * 64 + lane];
        al += bflo(vv) * bflo(xw);
        ah += bfhi(vv) * bfhi(xw);
    }
    outlh[(size_t)wid * 64 + lane] = packbf(fmaxf(al, 0.f), fmaxf(ah, 0.f));
}

// ---------------- phase C+D fused: masked aggregation + attention ----------------

__launch_bounds__(256) __global__
void k_agg(const u32* __restrict__ outlh, const int* __restrict__ ssrcf,
           const int* __restrict__ offsets,
           const u16* __restrict__ aLF, const u16* __restrict__ aHF,
           const u16* __restrict__ aLB, const u16* __restrict__ aHB,
           const u16* __restrict__ aLU, const u16* __restrict__ aHU,
           const u16* __restrict__ aM, const u16* __restrict__ a7, int N,
           float* __restrict__ out, const int* __restrict__ flag) {
    int isf32 = *flag;
    int wid = __builtin_amdgcn_readfirstlane((blockIdx.x * blockDim.x + threadIdx.x) >> 6);
    int lane = threadIdx.x & 63;
    if (wid >= N) return;
    int s = offsets[wid], e = offsets[wid + 1];
    int Nm1 = N - 1;
    float hetL = 0.f, hetH = 0.f, homL = 0.f, homH = 0.f, unkL = 0.f, unkH = 0.f;
    int j = s;
    for (; j + 8 <= e; j += 8) {
        u32 row[8];
        int sf[8];
#pragma unroll
        for (int t = 0; t < 8; t++) {
            sf[t] = ssrcf[j + t];         // scalar load (wave-uniform)
            int sj = min(sf[t] & 0xFFFFF, Nm1);
            row[t] = outlh[(size_t)sj * 64 + lane];  // vector gather, 8 in flight
        }
#pragma unroll
        for (int t = 0; t < 8; t++) {
            int fj = (sf[t] >> 20) & 3;   // wave-uniform branch
            float lo = bflo(row[t]), hi = bfhi(row[t]);
            if (fj == 0) { homL += lo; homH += hi; }
            else if (fj == 1) { hetL += lo; hetH += hi; }
            else { unkL += lo; unkH += hi; }
        }
    }
    for (; j < e; j++) {
        int t = ssrcf[j];
        int sj = min(t & 0xFFFFF, Nm1);
        int fj = (t >> 20) & 3;
        u32 o = outlh[(size_t)sj * 64 + lane];
        float lo = bflo(o), hi = bfhi(o);
        if (fj == 0) { homL += lo; homH += hi; }
        else if (fj == 1) { hetL += lo; hetH += hi; }
        else { unkL += lo; unkH += hi; }
    }
    float mv = out[(size_t)wid * 64 + lane];  // omlp staged in d_out (f32)

    float d0 = wave_sum(hetL * ldf(aLF, lane, isf32));
    float d1 = wave_sum(hetH * ldf(aHF, lane, isf32));
    float d2 = wave_sum(homL * ldf(aLB, lane, isf32));
    float d3 = wave_sum(homH * ldf(aHB, lane, isf32));
    float d4 = wave_sum(unkL * ldf(aLU, lane, isf32));
    float d5 = wave_sum(unkH * ldf(aHU, lane, isf32));
    float d6 = wave_sum(mv * ldf(aM, lane, isf32));

    float f[7];
    f[0] = 1.f / (1.f + expf(-d0));
    f[1] = 1.f / (1.f + expf(-d1));
    f[2] = 1.f / (1.f + expf(-d2));
    f[3] = 1.f / (1.f + expf(-d3));
    f[4] = 1.f / (1.f + expf(-d4));
    f[5] = 1.f / (1.f + expf(-d5));
    f[6] = 1.f / (1.f + expf(-d6));

    float z[7];
#pragma unroll
    for (int jj = 0; jj < 7; jj++) {
        float acc = 0.f;
#pragma unroll
        for (int i = 0; i < 7; i++) acc += f[i] * ldf(a7, i * 7 + jj, isf32);
        z[jj] = acc * (1.f / 7.f);
    }
    float m = z[0];
#pragma unroll
    for (int jj = 1; jj < 7; jj++) m = fmaxf(m, z[jj]);
    float wsum = 0.f;
    float wv[7];
#pragma unroll
    for (int jj = 0; jj < 7; jj++) { wv[jj] = expf(z[jj] - m); wsum += wv[jj]; }

    float o = wv[0] * hetL + wv[1] * hetH + wv[2] * homL + wv[3] * homH + wv[4] * unkL +
              wv[5] * unkH + wv[6] * mv;
    o *= 7.f / wsum;
    out[(size_t)wid * 64 + lane] = sanitize(o, 333.f);
}

// ---------------- launcher ----------------

extern "C" void kernel_launch(void* const* d_in, const int* in_sizes, int n_in, void* d_out,
                              int out_size, void* d_ws, size_t ws_size, hipStream_t stream) {
    const u16* x = (const u16*)d_in[0];
    const u16* avl = (const u16*)d_in[1];
    const u16* avh = (const u16*)d_in[2];
    const u16* wl = (const u16*)d_in[3];
    const u16* wh = (const u16*)d_in[4];
    const u16* wm = (const u16*)d_in[5];
    const u16* aLF = (const u16*)d_in[6];
    const u16* aHF = (const u16*)d_in[7];
    const u16* aLB = (const u16*)d_in[8];
    const u16* aHB = (const u16*)d_in[9];
    const u16* aLU = (const u16*)d_in[10];
    const u16* aHU = (const u16*)d_in[11];
    const u16* aM = (const u16*)d_in[12];
    const u16* a7 = (const u16*)d_in[13];
    const int* esrc = (const int*)d_in[14];
    const int* edst = (const int*)d_in[15];
    const int* lab = (const int*)d_in[16];
    float* out = (float*)d_out;  // reference output is jnp.float32

    const int N = in_sizes[0] / 64;
    const int E = in_sizes[1];

    char* w = (char*)d_ws;
    size_t off = 0;
    auto alloc = [&](size_t bytes) -> char* {
        char* p = w + off;
        off += (bytes + 255) & ~(size_t)255;
        return p;
    };
    int* flag = (int*)alloc(256);
    int* offsets = (int*)alloc((size_t)(N + 1) * 4);
    int* degcur = (int*)alloc((size_t)2 * N * 4);
    int* bsum = (int*)alloc(256 * 4);
    int* boff = (int*)alloc(256 * 4);
    int* ssrcf = (int*)alloc((size_t)E * 4);
    u32* svlh = (u32*)alloc((size_t)E * 4);
    u32* xwlh = (u32*)alloc((size_t)N * 64 * 4);
    u32* outlh = (u32*)alloc((size_t)N * 64 * 4);
    int* deg = degcur;
    int* cursor = degcur + N;

    if (ws_size < off) {
        k_sentinel<<<(out_size + 255) / 256, 256, 0, stream>>>(out, out_size, 1000.0f);
        return;
    }

    int NB = (N + 1023) / 1024;  // 98 for N=100000; must be <= 256

    k_zero_sniff<<<(2 * N + 255) / 256, 256, 0, stream>>>(degcur, 2 * N, x, flag);
    k_hist<<<(E + 255) / 256, 256, 0, stream>>>(edst, E, deg);
    k_scan_partial<<<NB, 256, 0, stream>>>(deg, N, bsum);
    k_scan_bsum<<<1, 256, 0, stream>>>(bsum, NB, boff);
    k_scan_final<<<NB, 256, 0, stream>>>(deg, N, boff, offsets, E);
    k_scatter<<<(E + 255) / 256, 256, 0, stream>>>(esrc, edst, avl, avh, lab, E, offsets, cursor,
                                                   ssrcf, svlh, flag);

    k_gemm<<<512, 256, 0, stream>>>(x, wl, wh, wm, N, xwlh, out /* omlp staged in d_out */, flag);

    int nodeBlocks = (N * 64 + 255) / 256;
    k_spmm<<<nodeBlocks, 256, 0, stream>>>(xwlh, ssrcf, svlh, offsets, N, outlh);
    k_agg<<<nodeBlocks, 256, 0, stream>>>(outlh, ssrcf, offsets, aLF, aHF, aLB, aHB, aLU, aHU, aM,
                                          a7, N, out, flag);
}